// Round 3
// baseline (953.232 us; speedup 1.0000x reference)
//
#include <hip/hip_runtime.h>
#include <math.h>
#include <stdint.h>

#define N_NODES 50000
#define N_EDGES 800000
#define EDGE_BLOCKS 2500
#define TILES_PER_BLOCK 5      // 2500 * 5 * 64 = 800000 edges
#define NCHUNK 256
#define CHN 196                // 256*196 = 50176 >= 50000

typedef __attribute__((ext_vector_type(8))) short short8;   // 8 bf16 (4 VGPRs)
typedef __attribute__((ext_vector_type(4))) float f32x4;

__device__ inline unsigned short bf16_rne(float x) {
    unsigned u = __float_as_uint(x);
    unsigned r = u + 0x7FFFu + ((u >> 16) & 1u);
    return (unsigned short)(r >> 16);
}
__device__ inline float bf16_to_f32(unsigned short h) {
    return __uint_as_float(((unsigned)h) << 16);
}

// ---------------- K1: node GEMM  X(N x 64) @ W(64 x 64) + b -> Q/K/V -------
__global__ __launch_bounds__(256) void node_gemm(
    const float* __restrict__ x,
    const float* __restrict__ Wq, const float* __restrict__ bq,
    const float* __restrict__ Wk, const float* __restrict__ bk,
    const float* __restrict__ Wv, const float* __restrict__ bv,
    float* __restrict__ Qo, float* __restrict__ Ko, float* __restrict__ Vo)
{
    const int c = blockIdx.y;
    const float* W = (c == 0) ? Wq : (c == 1) ? Wk : Wv;
    const float* b = (c == 0) ? bq : (c == 1) ? bk : bv;
    float* outp    = (c == 0) ? Qo : (c == 1) ? Ko : Vo;

    __shared__ float Xs[64][68];
    __shared__ float Ws[64][64];
    const int t  = threadIdx.x;
    const int n0 = blockIdx.x * 64;

    for (int i = 0; i < 4; i++) {
        int fi = t + i * 256;
        int row = fi >> 4, c4 = (fi & 15) * 4;
        float4 v = make_float4(0.f, 0.f, 0.f, 0.f);
        if (n0 + row < N_NODES) v = *(const float4*)&x[(size_t)(n0 + row) * 64 + c4];
        *(float4*)&Xs[row][c4] = v;
    }
    for (int i = 0; i < 4; i++) {
        int fi = t + i * 256;
        int row = fi >> 4, c4 = (fi & 15) * 4;
        *(float4*)&Ws[row][c4] = *(const float4*)&W[(size_t)row * 64 + c4];
    }
    __syncthreads();

    const int tx = t & 15, ty = t >> 4;
    float acc[4][4] = {};
    #pragma unroll
    for (int k4 = 0; k4 < 64; k4 += 4) {
        float4 xv[4], wv[4];
        #pragma unroll
        for (int r = 0; r < 4; r++) xv[r] = *(const float4*)&Xs[ty * 4 + r][k4];
        #pragma unroll
        for (int j = 0; j < 4; j++) wv[j] = *(const float4*)&Ws[k4 + j][tx * 4];
        #pragma unroll
        for (int r = 0; r < 4; r++) {
            acc[r][0] += xv[r].x * wv[0].x + xv[r].y * wv[1].x + xv[r].z * wv[2].x + xv[r].w * wv[3].x;
            acc[r][1] += xv[r].x * wv[0].y + xv[r].y * wv[1].y + xv[r].z * wv[2].y + xv[r].w * wv[3].y;
            acc[r][2] += xv[r].x * wv[0].z + xv[r].y * wv[1].z + xv[r].z * wv[2].z + xv[r].w * wv[3].z;
            acc[r][3] += xv[r].x * wv[0].w + xv[r].y * wv[1].w + xv[r].z * wv[2].w + xv[r].w * wv[3].w;
        }
    }
    float4 bb = *(const float4*)&b[tx * 4];
    #pragma unroll
    for (int r = 0; r < 4; r++) {
        int row = n0 + ty * 4 + r;
        if (row < N_NODES) {
            float4 o;
            o.x = acc[r][0] + bb.x; o.y = acc[r][1] + bb.y;
            o.z = acc[r][2] + bb.z; o.w = acc[r][3] + bb.w;
            *(float4*)&outp[(size_t)row * 64 + tx * 4] = o;
        }
    }
}

// ---------------- bprep: We -> split-bf16 fragment arrays (runs once) ------
// Bhi_g/Blo_g layout matches edge_kernel frag reads: [(j*2+c)*512 + lane*8 + jj]
__global__ __launch_bounds__(256) void bprep_kernel(
    const float* __restrict__ We,
    unsigned short* __restrict__ Bhi_g, unsigned short* __restrict__ Blo_g)
{
    int tid = blockIdx.x * 256 + threadIdx.x;      // 2048 threads
    int k  = tid >> 5;
    int n4 = (tid & 31) * 4;
    float4 v4 = *(const float4*)&We[(size_t)k * 128 + n4];
    int c = k >> 5, qq = (k >> 3) & 3, jj = k & 7;
    float vv[4] = {v4.x, v4.y, v4.z, v4.w};
    #pragma unroll
    for (int u = 0; u < 4; u++) {
        int nn = n4 + u;
        int j  = nn >> 4;
        int ln = qq * 16 + (nn & 15);
        unsigned short hi = bf16_rne(vv[u]);
        unsigned short lo = bf16_rne(vv[u] - bf16_to_f32(hi));
        Bhi_g[(j * 2 + c) * 512 + ln * 8 + jj] = hi;
        Blo_g[(j * 2 + c) * 512 + ln * 8 + jj] = lo;
    }
}

// ---------------- sort-by-dst machinery -----------------------------------
__global__ void hist_kernel(const int* __restrict__ edge_index, int* __restrict__ counts)
{
    int e = blockIdx.x * 256 + threadIdx.x;
    if (e < N_EDGES) atomicAdd(&counts[edge_index[N_EDGES + e]], 1);
}

// Parallel 3-phase scan replacing the single-block scan (was 1 workgroup on
// one CU doing 50k uncoalesced loads; now 256 blocks, coalesced).
__global__ __launch_bounds__(256) void chunk_reduce_kernel(
    const int* __restrict__ counts, int* __restrict__ chunksum)
{
    __shared__ int red[256];
    const int c = blockIdx.x, t = threadIdx.x;
    int idx = c * CHN + t;
    int v = (t < CHN && idx < N_NODES) ? counts[idx] : 0;
    red[t] = v;
    __syncthreads();
    for (int s = 128; s > 0; s >>= 1) {
        if (t < s) red[t] += red[t + s];
        __syncthreads();
    }
    if (t == 0) chunksum[c] = red[0];
}

__global__ __launch_bounds__(256) void scan256_kernel(
    const int* __restrict__ chunksum, int* __restrict__ chunkoff,
    int* __restrict__ offsets)
{
    __shared__ int sh[256];
    const int t = threadIdx.x;
    int own = chunksum[t];
    sh[t] = own;
    __syncthreads();
    for (int off = 1; off < 256; off <<= 1) {
        int v = (t >= off) ? sh[t - off] : 0;
        __syncthreads();
        sh[t] += v;
        __syncthreads();
    }
    chunkoff[t] = sh[t] - own;                 // exclusive
    if (t == 255) offsets[N_NODES] = sh[255];
}

__global__ __launch_bounds__(256) void expand_kernel(
    const int* __restrict__ counts, const int* __restrict__ chunkoff,
    int* __restrict__ offsets, int* __restrict__ cursor)
{
    __shared__ int sh[256];
    const int c = blockIdx.x, t = threadIdx.x;
    int idx = c * CHN + t;
    int own = (t < CHN && idx < N_NODES) ? counts[idx] : 0;
    sh[t] = own;
    __syncthreads();
    for (int off = 1; off < 256; off <<= 1) {
        int v = (t >= off) ? sh[t - off] : 0;
        __syncthreads();
        sh[t] += v;
        __syncthreads();
    }
    int excl = sh[t] - own + chunkoff[c];
    if (t < CHN && idx < N_NODES) { offsets[idx] = excl; cursor[idx] = excl; }
}

// scatter emits (orig_edge, src, dst) so the fused edge kernel has all
// indices at the sorted position.
__global__ void scatter_kernel(const int* __restrict__ edge_index, int* __restrict__ cursor,
                               int4* __restrict__ es4)
{
    int e = blockIdx.x * 256 + threadIdx.x;
    if (e < N_EDGES) {
        int src = edge_index[e];
        int dst = edge_index[N_EDGES + e];
        int pos = atomicAdd(&cursor[dst], 1);
        es4[pos] = make_int4(e, src, dst, 0);
    }
}

// ---------------- K5: fused MFMA edge kernel -------------------------------
// Round-1 block-lockstep structure (barriers keep waves on the same tile =>
// L2 temporal locality; round-2 async variant cost +54MB fetch).  LDS diet:
// only hi-We frags in LDS (16KB); lo-We frags streamed from global (16KB hot
// set, L2-resident) in a second MFMA pass.  33.8KB LDS -> 4 blocks/CU.
__global__ __launch_bounds__(256, 4) void edge_kernel(
    const float* __restrict__ edge_attr,
    const int4*  __restrict__ es4,
    const unsigned short* __restrict__ Bhi_g,
    const unsigned short* __restrict__ Blo_g,
    const float* __restrict__ be,
    const float* __restrict__ Qws, const float* __restrict__ Kws,
    const float* __restrict__ Vws, const float* __restrict__ Aw,
    float* __restrict__ wE,
    float* __restrict__ WVacc, float* __restrict__ RVacc, float* __restrict__ Sacc)
{
    __shared__ __align__(16) unsigned short Bf[8192];    // hi frags only, 16KB
    __shared__ __align__(16) unsigned char  UB[17408];   // union: Af 16KB | kq 64x68 f32
    unsigned short* Af  = (unsigned short*)UB;
    float*          kqs = (float*)UB;

    const int t    = threadIdx.x;
    const int lane = t & 63;
    const int w    = t >> 6;
    const int n    = lane & 15;
    const int q    = lane >> 4;
    const int d    = n & 7;
    const int h2   = lane >> 3;
    const int d2l  = lane & 7;

    // ---- stage precomputed hi-We frags -> LDS (straight 16KB copy) ----
    for (int i = 0; i < 4; i++) {
        int o = t + i * 256;                  // 1024 ushort8 chunks
        *(short8*)&Bf[o * 8] = *(const short8*)&Bhi_g[o * 8];
    }
    float bev[8];
    #pragma unroll
    for (int j = 0; j < 8; j++) bev[j] = be[j * 16 + n];
    const float awv = Aw[d2l * 8 + h2];          // Aw[d][h]

    for (int it = 0; it < TILES_PER_BLOCK; it++) {
        const int tile  = blockIdx.x + it * EDGE_BLOCKS;
        const int pbase = tile * 64;             // sorted-position base

        __syncthreads();   // prev epilogue LDS reads done; Bf visible (1st iter)

        // ---- stage A tile (64 gathered edge_attr rows) as hi/lo frags ----
        for (int i = 0; i < 4; i++) {
            int fi  = t + i * 256;               // 1024 float4
            int row = fi >> 4;
            int c4  = (fi & 15) * 4;
            int eo  = es4[pbase + row].x;        // 16 threads share one line
            float4 v4 = *(const float4*)&edge_attr[(size_t)eo * 64 + c4];
            int ww = row >> 4, mm = row & 15;
            int c = c4 >> 5, qq = (c4 >> 3) & 3, j0 = c4 & 7;
            float vv[4] = {v4.x, v4.y, v4.z, v4.w};
            unsigned short hi[4], lo[4];
            #pragma unroll
            for (int u = 0; u < 4; u++) {
                hi[u] = bf16_rne(vv[u]);
                lo[u] = bf16_rne(vv[u] - bf16_to_f32(hi[u]));
            }
            int base_us = (qq * 16 + mm) * 8 + j0;
            *(ushort4*)&Af[((0 * 4 + ww) * 2 + c) * 512 + base_us] = make_ushort4(hi[0], hi[1], hi[2], hi[3]);
            *(ushort4*)&Af[((1 * 4 + ww) * 2 + c) * 512 + base_us] = make_ushort4(lo[0], lo[1], lo[2], lo[3]);
        }
        __syncthreads();   // A staged

        short8 ah0 = *(const short8*)&Af[((0 * 4 + w) * 2 + 0) * 512 + lane * 8];
        short8 ah1 = *(const short8*)&Af[((0 * 4 + w) * 2 + 1) * 512 + lane * 8];
        short8 al0 = *(const short8*)&Af[((1 * 4 + w) * 2 + 0) * 512 + lane * 8];
        short8 al1 = *(const short8*)&Af[((1 * 4 + w) * 2 + 1) * 512 + lane * 8];

        __syncthreads();   // A frags in regs -> union becomes kq buffer

        // ---- stage kq = K[src] + Q[dst]  (coalesced 256B/row gathers) ----
        for (int i = 0; i < 4; i++) {
            int fi  = t + i * 256;
            int row = fi >> 4;
            int c4  = (fi & 15) * 4;
            int4 es = es4[pbase + row];
            float4 kv = *(const float4*)&Kws[(size_t)es.y * 64 + c4];
            float4 qv = *(const float4*)&Qws[(size_t)es.z * 64 + c4];
            float4 o;
            o.x = kv.x + qv.x; o.y = kv.y + qv.y; o.z = kv.z + qv.z; o.w = kv.w + qv.w;
            *(float4*)&kqs[row * 68 + c4] = o;
        }

        // ---- preload V rows + dsts for this wave's 16 edges ----
        float vbuf[16];
        int   dsts[16];
        #pragma unroll
        for (int k = 0; k < 16; k++) {
            int4 es = es4[pbase + w * 16 + k];
            dsts[k] = es.z;
            vbuf[k] = Vws[(size_t)es.y * 64 + lane];
        }

        // ---- MFMA pass 1: hi-B from LDS (4 products per j) ----
        f32x4 acc[8];
        #pragma unroll
        for (int j = 0; j < 8; j++) acc[j] = (f32x4){0.f, 0.f, 0.f, 0.f};
        #pragma unroll
        for (int j = 0; j < 8; j++) {
            short8 bh0 = *(const short8*)&Bf[(j * 2 + 0) * 512 + lane * 8];
            short8 bh1 = *(const short8*)&Bf[(j * 2 + 1) * 512 + lane * 8];
            acc[j] = __builtin_amdgcn_mfma_f32_16x16x32_bf16(ah0, bh0, acc[j], 0, 0, 0);
            acc[j] = __builtin_amdgcn_mfma_f32_16x16x32_bf16(ah1, bh1, acc[j], 0, 0, 0);
            acc[j] = __builtin_amdgcn_mfma_f32_16x16x32_bf16(al0, bh0, acc[j], 0, 0, 0);
            acc[j] = __builtin_amdgcn_mfma_f32_16x16x32_bf16(al1, bh1, acc[j], 0, 0, 0);
        }
        // ---- MFMA pass 2: lo-B streamed from global (L2-hot 16KB) ----
        #pragma unroll
        for (int j = 0; j < 8; j++) {
            short8 bl0 = *(const short8*)&Blo_g[(j * 2 + 0) * 512 + lane * 8];
            short8 bl1 = *(const short8*)&Blo_g[(j * 2 + 1) * 512 + lane * 8];
            acc[j] = __builtin_amdgcn_mfma_f32_16x16x32_bf16(ah0, bl0, acc[j], 0, 0, 0);
            acc[j] = __builtin_amdgcn_mfma_f32_16x16x32_bf16(ah1, bl1, acc[j], 0, 0, 0);
        }
        __syncthreads();   // kq staged by all threads

        // ---- epilogue-1: scores; write back into kq slots (own-wave rows) --
        #pragma unroll
        for (int j = 0; j < 8; j++) {
            #pragma unroll
            for (int r = 0; r < 4; r++) {
                int e_loc = w * 16 + q * 4 + r;
                float Ev = acc[j][r] + bev[j];
                float pv = __shfl_xor(Ev, 8);
                float ew = (n < 8) ? Ev : pv;     // E_w[d]
                float eb = (n < 8) ? pv : Ev;     // E_b[d]
                float kq = kqs[e_loc * 68 + j * 8 + d];
                float v  = kq * ew;
                float sc = copysignf(sqrtf(fabsf(v)), v) + eb;
                sc = fmaxf(sc, 0.0f);
                kqs[e_loc * 68 + j * 8 + d] = sc; // dup lanes write same value
            }
        }
        // scattered wE store at original edge rows (256B/edge, 16 lanes each)
        #pragma unroll
        for (int i = 0; i < 4; i++) {
            int e_loc = w * 16 + i * 4 + q;
            int eo    = es4[pbase + e_loc].x;
            float4 o = *(const float4*)&kqs[e_loc * 68 + n * 4];
            *(float4*)&wE[(size_t)eo * 64 + n * 4] = o;
        }

        // ---- epilogue-2: segmented accumulate over this wave's 16 sorted
        //      edges; flush per-node partials via atomicAdd at run breaks ----
        float s_acc = 0.f, wvac = 0.f, rvac = 0.f;
        int cur = dsts[0];
        #pragma unroll
        for (int k = 0; k < 16; k++) {
            if (dsts[k] != cur) {                 // wave-uniform branch
                atomicAdd(&WVacc[(size_t)cur * 64 + lane], wvac);
                atomicAdd(&RVacc[(size_t)cur * 64 + lane], rvac);
                if (d2l == 0) atomicAdd(&Sacc[cur * 8 + h2], s_acc);
                s_acc = 0.f; wvac = 0.f; rvac = 0.f;
                cur = dsts[k];
            }
            float sc = kqs[(w * 16 + k) * 68 + lane];  // own-wave rows
            float tv = sc * awv;
            tv += __shfl_xor(tv, 1); tv += __shfl_xor(tv, 2); tv += __shfl_xor(tv, 4);
            tv = fminf(fmaxf(tv, -5.0f), 5.0f);
            float ev = __expf(tv);
            s_acc += ev;
            wvac  += ev * vbuf[k];
            rvac  += ev * sc;
        }
        atomicAdd(&WVacc[(size_t)cur * 64 + lane], wvac);
        atomicAdd(&RVacc[(size_t)cur * 64 + lane], rvac);
        if (d2l == 0) atomicAdd(&Sacc[cur * 8 + h2], s_acc);
    }
}

// ---------------- K7: per-node finalize  hout = (wv + VeRow.rv) / s --------
__global__ __launch_bounds__(256) void finalize_kernel(
    const float* __restrict__ WVacc, const float* __restrict__ RVacc,
    const float* __restrict__ Sacc,  const float* __restrict__ VeRow,
    float* __restrict__ hout)
{
    const int t = threadIdx.x;
    const int lane = t & 63;
    const int w = t >> 6;
    const int node = blockIdx.x * 4 + w;
    const int h = lane >> 3, dd = lane & 7;
    float wv = WVacc[(size_t)node * 64 + lane];
    float rv = RVacc[(size_t)node * 64 + lane];
    float s  = Sacc[node * 8 + h];
    float rvt = 0.f;
    int gbase = lane & ~7;
    #pragma unroll
    for (int dk = 0; dk < 8; dk++) {
        float rvd = __shfl(rv, gbase + dk);
        rvt += rvd * VeRow[dk * 64 + h * 8 + dd];
    }
    hout[(size_t)node * 64 + lane] = (wv + rvt) / (s + 1e-16f);
}

// ---------------- launch ----------------------------------------------------
extern "C" void kernel_launch(void* const* d_in, const int* in_sizes, int n_in,
                              void* d_out, int out_size, void* d_ws, size_t ws_size,
                              hipStream_t stream)
{
    const float* x         = (const float*)d_in[0];
    const float* edge_attr = (const float*)d_in[1];
    const int*   edge_index= (const int*)  d_in[2];
    const float* Wq = (const float*)d_in[3];  const float* bq = (const float*)d_in[4];
    const float* Wk = (const float*)d_in[5];  const float* bk = (const float*)d_in[6];
    const float* We = (const float*)d_in[7];  const float* be = (const float*)d_in[8];
    const float* Wv = (const float*)d_in[9];  const float* bv = (const float*)d_in[10];
    const float* Aw = (const float*)d_in[11]; const float* VeRow = (const float*)d_in[12];

    float* hout = (float*)d_out;                       // (N, 64)
    float* wE   = hout + (size_t)N_NODES * 64;         // (E, 64)

    float* Q     = (float*)d_ws;
    float* K     = Q + (size_t)N_NODES * 64;
    float* V     = K + (size_t)N_NODES * 64;
    float* WVacc = V + (size_t)N_NODES * 64;           // (N,64)
    float* RVacc = WVacc + (size_t)N_NODES * 64;       // (N,64)
    float* Sacc  = RVacc + (size_t)N_NODES * 64;       // (N,8)
    int* counts   = (int*)(Sacc + (size_t)N_NODES * 8);
    int* offsets  = counts + N_NODES;                  // N+1 entries
    int* cursor   = offsets + N_NODES + 1;
    int* chunksum = cursor + N_NODES + 1;              // 256
    int* chunkoff = chunksum + NCHUNK;                 // 256
    unsigned short* Bhi_g = (unsigned short*)(chunkoff + NCHUNK);  // 8192 us
    unsigned short* Blo_g = Bhi_g + 8192;                          // 8192 us
    int4* es4     = (int4*)(((uintptr_t)(Blo_g + 8192) + 15) & ~(uintptr_t)15);

    hipMemsetAsync(counts, 0, N_NODES * sizeof(int), stream);
    hipMemsetAsync(WVacc, 0, (size_t)N_NODES * 136 * sizeof(float), stream);  // WV+RV+S
    node_gemm<<<dim3(782, 3), 256, 0, stream>>>(x, Wq, bq, Wk, bk, Wv, bv, Q, K, V);
    bprep_kernel<<<8, 256, 0, stream>>>(We, Bhi_g, Blo_g);
    hist_kernel<<<(N_EDGES + 255) / 256, 256, 0, stream>>>(edge_index, counts);
    chunk_reduce_kernel<<<NCHUNK, 256, 0, stream>>>(counts, chunksum);
    scan256_kernel<<<1, 256, 0, stream>>>(chunksum, chunkoff, offsets);
    expand_kernel<<<NCHUNK, 256, 0, stream>>>(counts, chunkoff, offsets, cursor);
    scatter_kernel<<<(N_EDGES + 255) / 256, 256, 0, stream>>>(edge_index, cursor, es4);
    edge_kernel<<<EDGE_BLOCKS, 256, 0, stream>>>(edge_attr, es4, Bhi_g, Blo_g, be,
                                                 Q, K, V, Aw, wE, WVacc, RVacc, Sacc);
    finalize_kernel<<<N_NODES / 4, 256, 0, stream>>>(WVacc, RVacc, Sacc, VeRow, hout);
}

// Round 4
// 675.264 us; speedup vs baseline: 1.4116x; 1.4116x over previous
//
#include <hip/hip_runtime.h>
#include <math.h>
#include <stdint.h>

#define N_NODES 50000
#define N_EDGES 800000
#define EDGE_BLOCKS 2500
#define TILES_PER_BLOCK 5      // 2500 * 5 * 64 = 800000 edges
#define NCHUNK 256
#define CHN 196                // 256*196 = 50176 >= 50000

#define GEMM_BLOCKS 2346       // 782 * 3
#define BPREP_BLOCKS 8
#define HIST_BLOCKS 3125

typedef __attribute__((ext_vector_type(8))) short short8;   // 8 bf16 (4 VGPRs)
typedef __attribute__((ext_vector_type(4))) float f32x4;

__device__ inline unsigned short bf16_rne(float x) {
    unsigned u = __float_as_uint(x);
    unsigned r = u + 0x7FFFu + ((u >> 16) & 1u);
    return (unsigned short)(r >> 16);
}
__device__ inline float bf16_to_f32(unsigned short h) {
    return __uint_as_float(((unsigned)h) << 16);
}

// ---------------- K_A: fused prep  (node GEMM | We-frag prep | dst hist) ---
// blocks [0,2346): Q/K/V GEMM; [2346,2354): We -> split-bf16 frag array Bg;
// [2354,5479): histogram of dst.
__global__ __launch_bounds__(256) void prep_kernel(
    const float* __restrict__ x,
    const float* __restrict__ Wq, const float* __restrict__ bq,
    const float* __restrict__ Wk, const float* __restrict__ bk,
    const float* __restrict__ Wv, const float* __restrict__ bv,
    const float* __restrict__ We,
    const int*   __restrict__ edge_index,
    float* __restrict__ Qo, float* __restrict__ Ko, float* __restrict__ Vo,
    unsigned short* __restrict__ Bg, int* __restrict__ counts)
{
    const int b = blockIdx.x;
    const int t = threadIdx.x;

    if (b >= GEMM_BLOCKS + BPREP_BLOCKS) {            // ---- hist ----
        int e = (b - GEMM_BLOCKS - BPREP_BLOCKS) * 256 + t;
        if (e < N_EDGES) atomicAdd(&counts[edge_index[N_EDGES + e]], 1);
        return;
    }
    if (b >= GEMM_BLOCKS) {                           // ---- bprep ----
        int tid = (b - GEMM_BLOCKS) * 256 + t;        // 2048 threads
        int k  = tid >> 5;
        int n4 = (tid & 31) * 4;
        float4 v4 = *(const float4*)&We[(size_t)k * 128 + n4];
        int c = k >> 5, qq = (k >> 3) & 3, jj = k & 7;
        float vv[4] = {v4.x, v4.y, v4.z, v4.w};
        #pragma unroll
        for (int u = 0; u < 4; u++) {
            int nn = n4 + u;
            int j  = nn >> 4;
            int ln = qq * 16 + (nn & 15);
            unsigned short hi = bf16_rne(vv[u]);
            unsigned short lo = bf16_rne(vv[u] - bf16_to_f32(hi));
            Bg[(j * 2 + c) * 512 + ln * 8 + jj] = hi;           // hi half
            Bg[8192 + (j * 2 + c) * 512 + ln * 8 + jj] = lo;    // lo half
        }
        return;
    }

    // ---- node GEMM  X(N x 64) @ W(64 x 64) + b ----
    const int c  = b / 782;
    const int bx = b - c * 782;
    const float* W = (c == 0) ? Wq : (c == 1) ? Wk : Wv;
    const float* bb_ = (c == 0) ? bq : (c == 1) ? bk : bv;
    float* outp    = (c == 0) ? Qo : (c == 1) ? Ko : Vo;

    __shared__ float Xs[64][68];
    __shared__ float Ws[64][64];
    const int n0 = bx * 64;

    for (int i = 0; i < 4; i++) {
        int fi = t + i * 256;
        int row = fi >> 4, c4 = (fi & 15) * 4;
        float4 v = make_float4(0.f, 0.f, 0.f, 0.f);
        if (n0 + row < N_NODES) v = *(const float4*)&x[(size_t)(n0 + row) * 64 + c4];
        *(float4*)&Xs[row][c4] = v;
    }
    for (int i = 0; i < 4; i++) {
        int fi = t + i * 256;
        int row = fi >> 4, c4 = (fi & 15) * 4;
        *(float4*)&Ws[row][c4] = *(const float4*)&W[(size_t)row * 64 + c4];
    }
    __syncthreads();

    const int tx = t & 15, ty = t >> 4;
    float acc[4][4] = {};
    #pragma unroll
    for (int k4 = 0; k4 < 64; k4 += 4) {
        float4 xv[4], wv[4];
        #pragma unroll
        for (int r = 0; r < 4; r++) xv[r] = *(const float4*)&Xs[ty * 4 + r][k4];
        #pragma unroll
        for (int j = 0; j < 4; j++) wv[j] = *(const float4*)&Ws[k4 + j][tx * 4];
        #pragma unroll
        for (int r = 0; r < 4; r++) {
            acc[r][0] += xv[r].x * wv[0].x + xv[r].y * wv[1].x + xv[r].z * wv[2].x + xv[r].w * wv[3].x;
            acc[r][1] += xv[r].x * wv[0].y + xv[r].y * wv[1].y + xv[r].z * wv[2].y + xv[r].w * wv[3].y;
            acc[r][2] += xv[r].x * wv[0].z + xv[r].y * wv[1].z + xv[r].z * wv[2].z + xv[r].w * wv[3].z;
            acc[r][3] += xv[r].x * wv[0].w + xv[r].y * wv[1].w + xv[r].z * wv[2].w + xv[r].w * wv[3].w;
        }
    }
    float4 bv4 = *(const float4*)&bb_[tx * 4];
    #pragma unroll
    for (int r = 0; r < 4; r++) {
        int row = n0 + ty * 4 + r;
        if (row < N_NODES) {
            float4 o;
            o.x = acc[r][0] + bv4.x; o.y = acc[r][1] + bv4.y;
            o.z = acc[r][2] + bv4.z; o.w = acc[r][3] + bv4.w;
            *(float4*)&outp[(size_t)row * 64 + tx * 4] = o;
        }
    }
}

// ---------------- parallel scan (2 kernels) --------------------------------
__global__ __launch_bounds__(256) void chunk_reduce_kernel(
    const int* __restrict__ counts, int* __restrict__ chunksum)
{
    __shared__ int red[256];
    const int c = blockIdx.x, t = threadIdx.x;
    int idx = c * CHN + t;
    int v = (t < CHN && idx < N_NODES) ? counts[idx] : 0;
    red[t] = v;
    __syncthreads();
    for (int s = 128; s > 0; s >>= 1) {
        if (t < s) red[t] += red[t + s];
        __syncthreads();
    }
    if (t == 0) chunksum[c] = red[0];
}

// expand with redundant in-block scan of the 256 chunksums (folds scan256 in)
__global__ __launch_bounds__(256) void expand_kernel(
    const int* __restrict__ counts, const int* __restrict__ chunksum,
    int* __restrict__ cursor)
{
    __shared__ int shc[256];
    __shared__ int sh[256];
    const int c = blockIdx.x, t = threadIdx.x;
    shc[t] = chunksum[t];
    __syncthreads();
    for (int off = 1; off < 256; off <<= 1) {
        int v = (t >= off) ? shc[t - off] : 0;
        __syncthreads();
        shc[t] += v;
        __syncthreads();
    }
    int co = (c > 0) ? shc[c - 1] : 0;           // exclusive chunk offset

    int idx = c * CHN + t;
    int own = (t < CHN && idx < N_NODES) ? counts[idx] : 0;
    sh[t] = own;
    __syncthreads();
    for (int off = 1; off < 256; off <<= 1) {
        int v = (t >= off) ? sh[t - off] : 0;
        __syncthreads();
        sh[t] += v;
        __syncthreads();
    }
    if (t < CHN && idx < N_NODES) cursor[idx] = sh[t] - own + co;
}

// scatter emits (orig_edge, src, dst) at the dst-sorted position.
__global__ void scatter_kernel(const int* __restrict__ edge_index, int* __restrict__ cursor,
                               int4* __restrict__ es4)
{
    int e = blockIdx.x * 256 + threadIdx.x;
    if (e < N_EDGES) {
        int src = edge_index[e];
        int dst = edge_index[N_EDGES + e];
        int pos = atomicAdd(&cursor[dst], 1);
        es4[pos] = make_int4(e, src, dst, 0);
    }
}

// ---------------- K5: fused MFMA edge kernel -------------------------------
// Round-1 lockstep structure, minus both scatter-stagings:
//  - Bf (We hi+lo frags, 32KB) filled by straight vectorized copy from the
//    prepped Bg array (round-1's scatter staging was ~2e7 conflict cycles).
//  - A-fragments loaded DIRECTLY from global into registers (each lane owns
//    its 16 f32), hi/lo split in-reg: no Af LDS, no conflicts, 2 fewer
//    barriers.
//  - kq buffer is per-WAVE (4352B slice): every remaining LDS producer ->
//    consumer is same-wave in-order; the single per-tile barrier only keeps
//    waves tile-lockstep (L2 locality, round-2 lesson).
__global__ __launch_bounds__(256, 3) void edge_kernel(
    const float* __restrict__ edge_attr,
    const int4*  __restrict__ es4,
    const unsigned short* __restrict__ Bg,
    const float* __restrict__ be,
    const float* __restrict__ Qws, const float* __restrict__ Kws,
    const float* __restrict__ Vws, const float* __restrict__ Aw,
    float* __restrict__ wE,
    float* __restrict__ WVacc, float* __restrict__ RVacc, float* __restrict__ Sacc)
{
    __shared__ __align__(16) unsigned short Bf[16384];   // hi|lo We frags, 32KB
    __shared__ __align__(16) unsigned char  UB[17408];   // 4 x 4352B per-wave kq

    const int t    = threadIdx.x;
    const int lane = t & 63;
    const int w    = t >> 6;
    const int n    = lane & 15;
    const int q    = lane >> 4;
    const int d    = n & 7;
    const int h2   = lane >> 3;
    const int d2l  = lane & 7;

    float* kqw = (float*)(UB + w * 4352);                // 16 x 68 f32

    // ---- Bf <- Bg: straight 32KB copy, conflict-free ----
    for (int i = 0; i < 8; i++) {
        int o = t + i * 256;                             // 2048 short8 chunks
        *(short8*)&Bf[o * 8] = *(const short8*)&Bg[o * 8];
    }
    float bev[8];
    #pragma unroll
    for (int j = 0; j < 8; j++) bev[j] = be[j * 16 + n];
    const float awv = Aw[d2l * 8 + h2];                  // Aw[d][h]

    for (int it = 0; it < TILES_PER_BLOCK; it++) {
        const int tile  = blockIdx.x + it * EDGE_BLOCKS;
        const int wbase = tile * 64 + w * 16;            // this wave's 16 edges

        __syncthreads();   // lockstep pacing; Bf visible (1st iter)

        // ---- A-frags: direct global loads (lane owns row lane&15, k-octet
        //      lane>>4 of both 32-wide chunks) ----
        int eoA = es4[wbase + (lane & 15)].x;
        const float* arow = &edge_attr[(size_t)eoA * 64 + (lane >> 4) * 8];
        float4 a0 = *(const float4*)&arow[0];
        float4 a1 = *(const float4*)&arow[4];
        float4 a2 = *(const float4*)&arow[32];
        float4 a3 = *(const float4*)&arow[36];

        // ---- stage OWN kq = K[src] + Q[dst] rows (wave-local) ----
        #pragma unroll
        for (int i = 0; i < 4; i++) {
            int idx = i * 64 + lane;
            int m   = idx >> 4;
            int c4  = (idx & 15) * 4;
            int4 es = es4[wbase + m];
            float4 kv = *(const float4*)&Kws[(size_t)es.y * 64 + c4];
            float4 qv = *(const float4*)&Qws[(size_t)es.z * 64 + c4];
            float4 o;
            o.x = kv.x + qv.x; o.y = kv.y + qv.y; o.z = kv.z + qv.z; o.w = kv.w + qv.w;
            *(float4*)&kqw[m * 68 + c4] = o;
        }

        // ---- preload OWN V rows + dsts ----
        float vbuf[16];
        int   dsts[16];
        #pragma unroll
        for (int k = 0; k < 16; k++) {
            int4 es = es4[wbase + k];
            dsts[k] = es.z;
            vbuf[k] = Vws[(size_t)es.y * 64 + lane];
        }

        // ---- hi/lo split of A in registers ----
        float c0[8] = {a0.x, a0.y, a0.z, a0.w, a1.x, a1.y, a1.z, a1.w};
        float c1[8] = {a2.x, a2.y, a2.z, a2.w, a3.x, a3.y, a3.z, a3.w};
        short8 ah0, al0, ah1, al1;
        #pragma unroll
        for (int j = 0; j < 8; j++) {
            unsigned short hi = bf16_rne(c0[j]);
            ah0[j] = (short)hi;
            al0[j] = (short)bf16_rne(c0[j] - bf16_to_f32(hi));
        }
        #pragma unroll
        for (int j = 0; j < 8; j++) {
            unsigned short hi = bf16_rne(c1[j]);
            ah1[j] = (short)hi;
            al1[j] = (short)bf16_rne(c1[j] - bf16_to_f32(hi));
        }

        // ---- MFMA: acc[j] over 8 n-tiles, 2 K-chunks, 3 split products ----
        f32x4 acc[8];
        #pragma unroll
        for (int j = 0; j < 8; j++) acc[j] = (f32x4){0.f, 0.f, 0.f, 0.f};
        #pragma unroll
        for (int j = 0; j < 8; j++) {
            short8 bh0 = *(const short8*)&Bf[(j * 2 + 0) * 512 + lane * 8];
            short8 bh1 = *(const short8*)&Bf[(j * 2 + 1) * 512 + lane * 8];
            short8 bl0 = *(const short8*)&Bf[8192 + (j * 2 + 0) * 512 + lane * 8];
            short8 bl1 = *(const short8*)&Bf[8192 + (j * 2 + 1) * 512 + lane * 8];
            acc[j] = __builtin_amdgcn_mfma_f32_16x16x32_bf16(ah0, bh0, acc[j], 0, 0, 0);
            acc[j] = __builtin_amdgcn_mfma_f32_16x16x32_bf16(ah1, bh1, acc[j], 0, 0, 0);
            acc[j] = __builtin_amdgcn_mfma_f32_16x16x32_bf16(al0, bh0, acc[j], 0, 0, 0);
            acc[j] = __builtin_amdgcn_mfma_f32_16x16x32_bf16(al1, bh1, acc[j], 0, 0, 0);
            acc[j] = __builtin_amdgcn_mfma_f32_16x16x32_bf16(ah0, bl0, acc[j], 0, 0, 0);
            acc[j] = __builtin_amdgcn_mfma_f32_16x16x32_bf16(ah1, bl1, acc[j], 0, 0, 0);
        }

        // ---- epilogue-1: scores -> own kq slots (same-wave, in-order) ----
        #pragma unroll
        for (int j = 0; j < 8; j++) {
            #pragma unroll
            for (int r = 0; r < 4; r++) {
                int el = q * 4 + r;              // local edge row 0..15
                float Ev = acc[j][r] + bev[j];
                float pv = __shfl_xor(Ev, 8);
                float ew = (n < 8) ? Ev : pv;    // E_w[d]
                float eb = (n < 8) ? pv : Ev;    // E_b[d]
                float kq = kqw[el * 68 + j * 8 + d];
                float v  = kq * ew;
                float sc = copysignf(sqrtf(fabsf(v)), v) + eb;
                sc = fmaxf(sc, 0.0f);
                kqw[el * 68 + j * 8 + d] = sc;   // dup lanes write same value
            }
        }
        // scattered wE store at original edge rows (256B/edge, 16 lanes each)
        #pragma unroll
        for (int i = 0; i < 4; i++) {
            int el = i * 4 + q;
            int eo = es4[wbase + el].x;
            float4 o = *(const float4*)&kqw[el * 68 + n * 4];
            *(float4*)&wE[(size_t)eo * 64 + n * 4] = o;
        }

        // ---- epilogue-2: segmented accumulate over own 16 sorted edges ----
        float s_acc = 0.f, wvac = 0.f, rvac = 0.f;
        int cur = dsts[0];
        #pragma unroll
        for (int k = 0; k < 16; k++) {
            if (dsts[k] != cur) {                 // wave-uniform branch
                atomicAdd(&WVacc[(size_t)cur * 64 + lane], wvac);
                atomicAdd(&RVacc[(size_t)cur * 64 + lane], rvac);
                if (d2l == 0) atomicAdd(&Sacc[cur * 8 + h2], s_acc);
                s_acc = 0.f; wvac = 0.f; rvac = 0.f;
                cur = dsts[k];
            }
            float sc = kqw[k * 68 + lane];        // own-wave rows
            float tv = sc * awv;
            tv += __shfl_xor(tv, 1); tv += __shfl_xor(tv, 2); tv += __shfl_xor(tv, 4);
            tv = fminf(fmaxf(tv, -5.0f), 5.0f);
            float ev = __expf(tv);
            s_acc += ev;
            wvac  += ev * vbuf[k];
            rvac  += ev * sc;
        }
        atomicAdd(&WVacc[(size_t)cur * 64 + lane], wvac);
        atomicAdd(&RVacc[(size_t)cur * 64 + lane], rvac);
        if (d2l == 0) atomicAdd(&Sacc[cur * 8 + h2], s_acc);
    }
}

// ---------------- K7: per-node finalize  hout = (wv + VeRow.rv) / s --------
__global__ __launch_bounds__(256) void finalize_kernel(
    const float* __restrict__ WVacc, const float* __restrict__ RVacc,
    const float* __restrict__ Sacc,  const float* __restrict__ VeRow,
    float* __restrict__ hout)
{
    const int t = threadIdx.x;
    const int lane = t & 63;
    const int w = t >> 6;
    const int node = blockIdx.x * 4 + w;
    const int h = lane >> 3, dd = lane & 7;
    float wv = WVacc[(size_t)node * 64 + lane];
    float rv = RVacc[(size_t)node * 64 + lane];
    float s  = Sacc[node * 8 + h];
    float rvt = 0.f;
    int gbase = lane & ~7;
    #pragma unroll
    for (int dk = 0; dk < 8; dk++) {
        float rvd = __shfl(rv, gbase + dk);
        rvt += rvd * VeRow[dk * 64 + h * 8 + dd];
    }
    hout[(size_t)node * 64 + lane] = (wv + rvt) / (s + 1e-16f);
}

// ---------------- launch ----------------------------------------------------
extern "C" void kernel_launch(void* const* d_in, const int* in_sizes, int n_in,
                              void* d_out, int out_size, void* d_ws, size_t ws_size,
                              hipStream_t stream)
{
    const float* x         = (const float*)d_in[0];
    const float* edge_attr = (const float*)d_in[1];
    const int*   edge_index= (const int*)  d_in[2];
    const float* Wq = (const float*)d_in[3];  const float* bq = (const float*)d_in[4];
    const float* Wk = (const float*)d_in[5];  const float* bk = (const float*)d_in[6];
    const float* We = (const float*)d_in[7];  const float* be = (const float*)d_in[8];
    const float* Wv = (const float*)d_in[9];  const float* bv = (const float*)d_in[10];
    const float* Aw = (const float*)d_in[11]; const float* VeRow = (const float*)d_in[12];

    float* hout = (float*)d_out;                       // (N, 64)
    float* wE   = hout + (size_t)N_NODES * 64;         // (E, 64)

    float* Q     = (float*)d_ws;
    float* K     = Q + (size_t)N_NODES * 64;
    float* V     = K + (size_t)N_NODES * 64;
    float* WVacc = V + (size_t)N_NODES * 64;           // (N,64)
    float* RVacc = WVacc + (size_t)N_NODES * 64;       // (N,64)
    float* Sacc  = RVacc + (size_t)N_NODES * 64;       // (N,8)
    int* counts   = (int*)(Sacc + (size_t)N_NODES * 8);
    int* cursor   = counts + N_NODES;
    int* chunksum = cursor + N_NODES;                  // 256
    unsigned short* Bg = (unsigned short*)(chunksum + NCHUNK);     // 16384 us
    int4* es4     = (int4*)(((uintptr_t)(Bg + 16384) + 15) & ~(uintptr_t)15);

    hipMemsetAsync(counts, 0, N_NODES * sizeof(int), stream);
    hipMemsetAsync(WVacc, 0, (size_t)N_NODES * 136 * sizeof(float), stream);  // WV+RV+S
    prep_kernel<<<GEMM_BLOCKS + BPREP_BLOCKS + HIST_BLOCKS, 256, 0, stream>>>(
        x, Wq, bq, Wk, bk, Wv, bv, We, edge_index, Q, K, V, Bg, counts);
    chunk_reduce_kernel<<<NCHUNK, 256, 0, stream>>>(counts, chunksum);
    expand_kernel<<<NCHUNK, 256, 0, stream>>>(counts, chunksum, cursor);
    scatter_kernel<<<(N_EDGES + 255) / 256, 256, 0, stream>>>(edge_index, cursor, es4);
    edge_kernel<<<EDGE_BLOCKS, 256, 0, stream>>>(edge_attr, es4, Bg, be,
                                                 Q, K, V, Aw, wE, WVacc, RVacc, Sacc);
    finalize_kernel<<<N_NODES / 4, 256, 0, stream>>>(WVacc, RVacc, Sacc, VeRow, hout);
}